// Round 12
// baseline (4216.782 us; speedup 1.0000x reference)
//
#include <hip/hip_runtime.h>

typedef __attribute__((ext_vector_type(8))) short short8;
typedef __attribute__((ext_vector_type(4))) float f32x4;
typedef __attribute__((ext_vector_type(4))) int   i32x4;

#define MFMA(a,b,c)  __builtin_amdgcn_mfma_f32_16x16x32_bf16(a,b,c,0,0,0)
#define MFMAI(a,b,c) __builtin_amdgcn_mfma_i32_16x16x64_i8(a,b,c,0,0,0)

// Problem dims
#define S_LEN 128
#define IN_D  8
#define HID   512
#define NL    3
#define H8STR 528       // i8 h row stride (bytes)
#define LOG2E  1.4426950408889634f
#define LOG2E2 2.8853901617779268f

// ws layout (bytes)
#define OFF_WI8  0                       // [3][32nt][8kk][3g][64][16B] i8 = 2,359,296
#define OFF_WIH  (2359296)               // [3][32][3][64][8] bf16        =   294,912
#define OFF_SW   (2359296 + 294912)      // 4608 f32 dequant scales       =    18,432
#define OFF_SWI  (OFF_SW + 18432)        // 4608 f32 inv scales           =    18,432
#define OFF_FLAG (OFF_SWI + 18432)       // 512 int                       =     2,048
#define OFF_XCHG (OFF_FLAG + 2048)       // 512 blk * 2 slot * 4 KB      = 4,194,304

__device__ __forceinline__ unsigned short f2bf(float f){
  unsigned u = __float_as_uint(f);
  u += 0x7FFFu + ((u >> 16) & 1u);
  return (unsigned short)(u >> 16);
}
__device__ __forceinline__ float fexp2(float x){ return __builtin_amdgcn_exp2f(x); }
__device__ __forceinline__ float frcp(float x){ return __builtin_amdgcn_rcpf(x); }

// Per-row absmax scales for Whh
__global__ void prep_scale(const float* __restrict__ Whh,
                           float* __restrict__ sw, float* __restrict__ swi){
  int row = blockIdx.x * 4 + (threadIdx.x >> 6);
  int lane = threadIdx.x & 63;
  const float* src = Whh + (size_t)row * 512;
  float m = 0.f;
#pragma unroll
  for (int i = 0; i < 8; ++i) m = fmaxf(m, fabsf(src[lane + i * 64]));
#pragma unroll
  for (int off = 32; off; off >>= 1) m = fmaxf(m, (float)__shfl_xor(m, off));
  m = fmaxf(m, 1e-20f);
  if (lane == 0){ sw[row] = m / 127.f; swi[row] = 127.f / m; }
}

// Quantize+pack Whh -> i8 A-fragments (K=64), gate-interleaved per kk
__global__ void prep_wi8(const float* __restrict__ Whh, const float* __restrict__ swi,
                         unsigned char* __restrict__ Wp8){
  int gid = blockIdx.x * 256 + threadIdx.x;     // 147456 total
  int lane = gid & 63;
  int r = gid >> 6;
  int g  = r % 3;  r /= 3;
  int kk = r & 7;  r >>= 3;
  int nt = r & 31;
  int l  = r >> 5;
  int row = l * 1536 + g * 512 + nt * 16 + (lane & 15);
  int k0  = kk * 64 + (lane >> 4) * 16;
  const float* src = Whh + (size_t)row * 512 + k0;
  float si = swi[row];
  uint4 v = {0,0,0,0};
  unsigned w[4] = {0,0,0,0};
#pragma unroll
  for (int j = 0; j < 16; ++j){
    int q = (int)rintf(src[j] * si);
    q = q > 127 ? 127 : (q < -127 ? -127 : q);
    w[j >> 2] |= ((unsigned)(q & 0xFF)) << ((j & 3) * 8);
  }
  v.x = w[0]; v.y = w[1]; v.z = w[2]; v.w = w[3];
  *(uint4*)(Wp8 + (size_t)gid * 16) = v;
}

// Pack Wih -> zero-padded (K=8 of 32) bf16 A-fragments, prescaled to exp2 domain
__global__ void prep_wih(const float* __restrict__ Wih, unsigned short* __restrict__ Wip){
  int gid = blockIdx.x * 256 + threadIdx.x;     // 18432 total
  int lane = gid & 63;
  int r = gid >> 6;
  int g  = r % 3;  r /= 3;
  int nt = r & 31;
  int l  = r >> 5;
  float scl = (g == 2) ? LOG2E2 : LOG2E;
  unsigned short t[8] = {0,0,0,0,0,0,0,0};
  if ((lane >> 4) == 0){
    int n = g * 512 + nt * 16 + (lane & 15);
    const float* src = Wih + ((size_t)l * 1536 + n) * 8;
#pragma unroll
    for (int j = 0; j < 8; ++j) t[j] = f2bf(src[j] * scl);
  }
  uint4 v;
  v.x = t[0] | ((unsigned)t[1] << 16);
  v.y = t[2] | ((unsigned)t[3] << 16);
  v.z = t[4] | ((unsigned)t[5] << 16);
  v.w = t[6] | ((unsigned)t[7] << 16);
  *(uint4*)(Wip + (size_t)gid * 8) = v;
}

// Main: 512 blocks x 512 threads (8 waves), EXACTLY 2 blocks/CU (LDS 54.8 KB, VGPR<=128).
// 16 waves/CU (TLP of R11) x 128 VGPR/wave (ILP of R10): pool 16*128 = 2048 = exact fit.
// Quad (bid&~3 | 0..3) shares batch rows [b0,b0+32); each computes 128 of 512 cols.
// q = bid&3 == XCD%4 -> per-XCD weight slice 590 KB, L2-hot. 3-sibling i8 mailbox.
__global__ __launch_bounds__(512, 4) void gru_main(
    const float* __restrict__ x,
    const unsigned char* __restrict__ Wp8,
    const unsigned short* __restrict__ Wip,
    const float* __restrict__ bih,
    const float* __restrict__ bhh,
    const float* __restrict__ sw,
    float* __restrict__ out,
    int* __restrict__ flags,
    unsigned int* __restrict__ xchg)
{
  __shared__ __align__(16) unsigned char  hB8[2][32 * H8STR]; // 33,792 B (full 512 cols)
  __shared__ __align__(16) unsigned short xpack[2][1024];     //  4,096 B
  __shared__ __align__(16) float sBrz[3 * 256];               //  3,072 B (own quarter r|z)
  __shared__ __align__(16) float sBni[3 * 128];               //  1,536 B
  __shared__ __align__(16) float sBnh[3 * 128];               //  1,536 B
  __shared__ __align__(16) float sK[3 * 384];                 //  4,608 B
  __shared__ int   pad[1536];                                 //  6,144 B -> 54,784 total

  const int tid  = threadIdx.x;
  const int wv   = tid >> 6;          // 0..7
  const int lane = tid & 63;
  const int l15  = lane & 15;
  const int l4   = lane >> 4;

  const int bid  = blockIdx.x;
  const int q    = bid & 3;                    // col quadrant == XCD%4
  const int sib  = bid & ~3;
  const int b0   = (bid >> 2) * 32;
  const int lc   = wv * 16 + l4 * 4;           // local col (0..127), lane's first of 4
  const int colv = q * 128 + lc;               // global col
  const int ntc  = q * 8 + wv;                 // global 16-col tile index

  // pad liveness guard (flags never negative) — prevents LDS DCE (R8 lesson)
  if (flags[bid] == -1) pad[tid] = tid;

  const int q1 = (q + 1) & 3, q2 = (q + 2) & 3, q3 = (q + 3) & 3;
  unsigned int* xown = xchg + (size_t)bid * 2048;              // 2 slots x 1024 u32
  const unsigned int* p0 = xchg + (size_t)(sib | q1) * 2048 + tid;
  const unsigned int* p1 = xchg + (size_t)(sib | q2) * 2048 + tid;
  const unsigned int* p2 = xchg + (size_t)(sib | q3) * 2048 + tid;
  const int dbase = (tid >> 5) * H8STR + (tid & 31) * 4;       // copy dest rows 0..15 (+16 for k=1)
  const int d0 = dbase + q1 * 128, d1 = dbase + q2 * 128, d2 = dbase + q3 * 128;

  for (int i = tid; i < 2 * 32 * H8STR / 4; i += 512) ((unsigned*)hB8)[i] = 0;
  for (int i = tid; i < 768; i += 512){
    int l = i >> 8, c = i & 255;
    int gc = l * 1536 + ((c < 128) ? (q * 128 + c) : (512 + q * 128 + (c - 128)));
    sBrz[i] = (bih[gc] + bhh[gc]) * LOG2E;
  }
  if (tid < 384){
    int l = tid >> 7, c = tid & 127;
    int gc = l * 1536 + 1024 + q * 128 + c;
    sBni[tid] = bih[gc] * LOG2E2;
    sBnh[tid] = bhh[gc] * LOG2E2;
  }
  for (int i = tid; i < 1152; i += 512){
    int l = i / 384, rem = i % 384, g = rem >> 7, c = rem & 127;
    int row = l * 1536 + g * 512 + q * 128 + c;
    sK[i] = sw[row] * (1.f / 127.f) * (g == 2 ? LOG2E2 : LOG2E);
  }

  float hreg[2][4];   // [batch-frag][outcol q]
#pragma unroll
  for (int nf = 0; nf < 2; ++nf)
#pragma unroll
    for (int qq = 0; qq < 4; ++qq) hreg[nf][qq] = 0.f;

  // xpack writer: entry (m*64+ln)*8+j; thread covers entries tid (m=0) and tid+512 (m=1)
  const int xl = (tid >> 3) & 63;
  const size_t xbase  = ((size_t)(b0 + (xl & 15))) * (S_LEN * IN_D) + (tid & 7);
  const size_t xbase2 = xbase + (size_t)16 * (S_LEN * IN_D);
  const int xvalid = (xl < 16);
  {
    xpack[0][tid]       = f2bf(xvalid ? x[xbase]  : 0.f);
    xpack[0][tid + 512] = f2bf(xvalid ? x[xbase2] : 0.f);
  }
  __syncthreads();

  const int boff0 = l15 * H8STR + l4 * 16;        // h B-frag nf=0 (batch 0..15), bytes
  const int boff1 = boff0 + 16 * H8STR;           // nf=1 (batch 16..31)

  const unsigned char*  wklB = Wp8 + (size_t)ntc * (8 * 3 * 64 * 16) + (size_t)lane * 16;
  const unsigned short* wilB = Wip + (size_t)ntc * 3 * 512 + (size_t)lane * 8;

#define DO_KK(kkv) { \
    const int kk_ = (kkv); \
    const unsigned char* w_ = wkl + kk_ * 3072; \
    i32x4 wR = *(const i32x4*)(w_); \
    i32x4 wZ = *(const i32x4*)(w_ + 1024); \
    i32x4 wN = *(const i32x4*)(w_ + 2048); \
    i32x4 hb0 = *(const i32x4*)(hb8c + boff0 + kk_ * 64); \
    i32x4 hb1 = *(const i32x4*)(hb8c + boff1 + kk_ * 64); \
    aR[0] = MFMAI(wR, hb0, aR[0]);  aR[1] = MFMAI(wR, hb1, aR[1]); \
    aZ[0] = MFMAI(wZ, hb0, aZ[0]);  aZ[1] = MFMAI(wZ, hb1, aZ[1]); \
    aN[0] = MFMAI(wN, hb0, aN[0]);  aN[1] = MFMAI(wN, hb1, aN[1]); \
  }

  int cur = 0;
#pragma unroll 1
  for (int t = 0; t < S_LEN; ++t){
    const unsigned short* xp = &xpack[t & 1][0];
#pragma unroll 1
    for (int l = 0; l < NL; ++l){
      const int s    = t * NL + l;
      const int last = (s == S_LEN * NL - 1);
      const unsigned char* hb8c = hB8[cur];
      unsigned char*       hb8w = hB8[cur];
      unsigned char*       hb8n = hB8[cur ^ 1];
      const unsigned char*  wkl = wklB + (size_t)l * (32 * 8 * 3 * 64 * 16);
      const unsigned short* wil = wilB + (size_t)l * (32 * 3 * 512);

      // poll 3 sibling flags + issue 6 mailbox u32 loads; LDS writes deferred
      unsigned ca0=0, ca1=0, cb0=0, cb1=0, cc0=0, cc1=0;
      if (s > 0){
        for (;;){
          int f1 = __hip_atomic_load(&flags[sib | q1], __ATOMIC_RELAXED, __HIP_MEMORY_SCOPE_AGENT);
          int f2 = __hip_atomic_load(&flags[sib | q2], __ATOMIC_RELAXED, __HIP_MEMORY_SCOPE_AGENT);
          int f3 = __hip_atomic_load(&flags[sib | q3], __ATOMIC_RELAXED, __HIP_MEMORY_SCOPE_AGENT);
          if (f1 >= s && f2 >= s && f3 >= s) break;
          __builtin_amdgcn_s_sleep(4);
        }
        const int so = ((s - 1) & 1) * 1024;
        ca0 = __hip_atomic_load(p0 + so,       __ATOMIC_RELAXED, __HIP_MEMORY_SCOPE_AGENT);
        ca1 = __hip_atomic_load(p0 + so + 512, __ATOMIC_RELAXED, __HIP_MEMORY_SCOPE_AGENT);
        cb0 = __hip_atomic_load(p1 + so,       __ATOMIC_RELAXED, __HIP_MEMORY_SCOPE_AGENT);
        cb1 = __hip_atomic_load(p1 + so + 512, __ATOMIC_RELAXED, __HIP_MEMORY_SCOPE_AGENT);
        cc0 = __hip_atomic_load(p2 + so,       __ATOMIC_RELAXED, __HIP_MEMORY_SCOPE_AGENT);
        cc1 = __hip_atomic_load(p2 + so + 512, __ATOMIC_RELAXED, __HIP_MEMORY_SCOPE_AGENT);
      }

      // per-outcol bias/scale vectors (own-quarter slices)
      const f32x4 vR4  = *(const f32x4*)&sBrz[l * 256 + lc];
      const f32x4 vZ4  = *(const f32x4*)&sBrz[l * 256 + 128 + lc];
      const f32x4 vNi4 = *(const f32x4*)&sBni[l * 128 + lc];
      const f32x4 vNh4 = *(const f32x4*)&sBnh[l * 128 + lc];
      const f32x4 kR4  = *(const f32x4*)&sK[l * 384 + lc];
      const f32x4 kZ4  = *(const f32x4*)&sK[l * 384 + 128 + lc];
      const f32x4 kN4  = *(const f32x4*)&sK[l * 384 + 256 + lc];

      f32x4 gR[2], gZ[2], gN[2];
      gR[0] = vR4;  gR[1] = vR4;
      gZ[0] = vZ4;  gZ[1] = vZ4;
      gN[0] = vNi4; gN[1] = vNi4;

      // gi = Wih-frag (A) x x-frag (B)
      {
        short8 wiR = *(const short8*)(wil);
        short8 wiZ = *(const short8*)(wil + 512);
        short8 wiN = *(const short8*)(wil + 1024);
        short8 xb0 = *(const short8*)(xp + lane * 8);
        short8 xb1 = *(const short8*)(xp + 512 + lane * 8);
        gR[0] = MFMA(wiR, xb0, gR[0]);  gR[1] = MFMA(wiR, xb1, gR[1]);
        gZ[0] = MFMA(wiZ, xb0, gZ[0]);  gZ[1] = MFMA(wiZ, xb1, gZ[1]);
        gN[0] = MFMA(wiN, xb0, gN[0]);  gN[1] = MFMA(wiN, xb1, gN[1]);
      }

      i32x4 aR[2], aZ[2], aN[2];
#pragma unroll
      for (int nf = 0; nf < 2; ++nf){
        aR[nf] = (i32x4){0,0,0,0};
        aZ[nf] = (i32x4){0,0,0,0};
        aN[nf] = (i32x4){0,0,0,0};
      }

      // own-quarter kks (h cols this block wrote last step)
      DO_KK(q * 2);
      DO_KK(q * 2 + 1);

      // sibling-copy LDS writes + mid-barrier
      if (s > 0){
        *(unsigned*)(hb8w + d0)              = ca0;
        *(unsigned*)(hb8w + d0 + 16 * H8STR) = ca1;
        *(unsigned*)(hb8w + d1)              = cb0;
        *(unsigned*)(hb8w + d1 + 16 * H8STR) = cb1;
        *(unsigned*)(hb8w + d2)              = cc0;
        *(unsigned*)(hb8w + d2 + 16 * H8STR) = cc1;
      }
      __syncthreads();

      // sibling-quarter kks
      DO_KK(q1 * 2);  DO_KK(q1 * 2 + 1);
      DO_KK(q2 * 2);  DO_KK(q2 * 2 + 1);
      DO_KK(q3 * 2);  DO_KK(q3 * 2 + 1);

      // gates: exp2-domain, native rcp; lane owns (batch = nf*16+l15, outcols colv..+3)
      unsigned int* xob = xown + (s & 1) * 1024;
#pragma unroll
      for (int nf = 0; nf < 2; ++nf){
        unsigned pk = 0;
#pragma unroll
        for (int qq = 0; qq < 4; ++qq){
          float rp = gR[nf][qq] + (float)aR[nf][qq] * kR4[qq];
          float zp = gZ[nf][qq] + (float)aZ[nf][qq] * kZ4[qq];
          float r  = frcp(1.f + fexp2(-rp));
          float z  = frcp(1.f + fexp2(-zp));
          float an = gN[nf][qq] + r * ((float)aN[nf][qq] * kN4[qq] + vNh4[qq]);
          float n  = fmaf(-2.f, frcp(1.f + fexp2(an)), 1.f);
          float hn = fmaf(z, hreg[nf][qq] - n, n);
          hreg[nf][qq] = hn;
          int hq = (int)rintf(hn * 127.f);
          pk |= ((unsigned)(hq & 0xFF)) << (qq * 8);
        }
        int brow = nf * 16 + l15;
        *(unsigned*)(hb8n + brow * H8STR + colv) = pk;
        if (!last)
          __hip_atomic_store(xob + brow * 32 + wv * 4 + l4, pk,
                             __ATOMIC_RELAXED, __HIP_MEMORY_SCOPE_AGENT);
      }

      // stage x(t+1) before the end-of-step barrier
      if (l == NL - 1 && t < S_LEN - 1){
        xpack[(t + 1) & 1][tid]       = f2bf(xvalid ? x[xbase  + (size_t)(t + 1) * IN_D] : 0.f);
        xpack[(t + 1) & 1][tid + 512] = f2bf(xvalid ? x[xbase2 + (size_t)(t + 1) * IN_D] : 0.f);
      }

      if (!last){
        asm volatile("s_waitcnt vmcnt(0)" ::: "memory");   // mailbox stores drained
        __syncthreads();
        if (tid == 0)
          __hip_atomic_store(&flags[bid], s + 1, __ATOMIC_RELAXED, __HIP_MEMORY_SCOPE_AGENT);
      }
      cur ^= 1;
    }
  }
#undef DO_KK

  // epilogue: lane holds 4 consecutive out-cols per batch-frag -> dwordx4 stores
#pragma unroll
  for (int nf = 0; nf < 2; ++nf){
    f32x4 v = { hreg[nf][0], hreg[nf][1], hreg[nf][2], hreg[nf][3] };
    int brow = nf * 16 + l15;
    *(f32x4*)&out[((size_t)(b0 + brow)) * 512 + colv] = v;
  }

  if (flags[bid] == -2) out[0] = (float)pad[tid];   // pad liveness (never true)
}

extern "C" void kernel_launch(void* const* d_in, const int* in_sizes, int n_in,
                              void* d_out, int out_size, void* d_ws, size_t ws_size,
                              hipStream_t stream){
  const float* x   = (const float*)d_in[0];
  const float* Wih = (const float*)d_in[1];
  const float* Whh = (const float*)d_in[2];
  const float* bih = (const float*)d_in[3];
  const float* bhh = (const float*)d_in[4];

  unsigned char* ws = (unsigned char*)d_ws;
  unsigned char*  Wp8  = (unsigned char*)(ws + OFF_WI8);
  unsigned short* Wip  = (unsigned short*)(ws + OFF_WIH);
  float*          sw   = (float*)(ws + OFF_SW);
  float*          swi  = (float*)(ws + OFF_SWI);
  int*            flg  = (int*)(ws + OFF_FLAG);
  unsigned int*   xchg = (unsigned int*)(ws + OFF_XCHG);

  hipMemsetAsync(flg, 0, 512 * sizeof(int), stream);
  prep_scale<<<1152, 256, 0, stream>>>(Whh, sw, swi);
  prep_wi8  <<< 576, 256, 0, stream>>>(Whh, swi, Wp8);
  prep_wih  <<<  72, 256, 0, stream>>>(Wih, Wip);
  gru_main  <<< 512, 512, 0, stream>>>(x, Wp8, Wip, bih, bhh, sw, (float*)d_out, flg, xchg);
}

// Round 14
// 2743.342 us; speedup vs baseline: 1.5371x; 1.5371x over previous
//
#include <hip/hip_runtime.h>

typedef __attribute__((ext_vector_type(8))) short short8;
typedef __attribute__((ext_vector_type(4))) float f32x4;
typedef __attribute__((ext_vector_type(4))) int   i32x4;

#define MFMA(a,b,c)  __builtin_amdgcn_mfma_f32_16x16x32_bf16(a,b,c,0,0,0)
#define MFMAI(a,b,c) __builtin_amdgcn_mfma_i32_16x16x64_i8(a,b,c,0,0,0)

// Problem dims
#define S_LEN 128
#define IN_D  8
#define HID   512
#define NL    3
#define H8STR 528       // i8 h row stride (bytes)
#define LOG2E  1.4426950408889634f
#define LOG2E2 2.8853901617779268f

// ws layout (bytes)
#define OFF_WI8  0                       // [3][32nt][8kk][3g][64][16B] i8 = 2,359,296
#define OFF_WIH  (2359296)               // [3][32][3][64][8] bf16        =   294,912
#define OFF_SW   (2359296 + 294912)      // 4608 f32 dequant scales       =    18,432
#define OFF_SWI  (OFF_SW + 18432)        // 4608 f32 inv scales           =    18,432
#define OFF_FLAG (OFF_SWI + 18432)       // 256 int                       =     1,024
#define OFF_XCHG (OFF_FLAG + 1024)       // 256 blk * 2 slot * 8 KB       = 4,194,304

__device__ __forceinline__ unsigned short f2bf(float f){
  unsigned u = __float_as_uint(f);
  u += 0x7FFFu + ((u >> 16) & 1u);
  return (unsigned short)(u >> 16);
}
__device__ __forceinline__ float fexp2(float x){ return __builtin_amdgcn_exp2f(x); }
__device__ __forceinline__ float frcp(float x){ return __builtin_amdgcn_rcpf(x); }

// Per-row absmax scales for Whh
__global__ void prep_scale(const float* __restrict__ Whh,
                           float* __restrict__ sw, float* __restrict__ swi){
  int row = blockIdx.x * 4 + (threadIdx.x >> 6);
  int lane = threadIdx.x & 63;
  const float* src = Whh + (size_t)row * 512;
  float m = 0.f;
#pragma unroll
  for (int i = 0; i < 8; ++i) m = fmaxf(m, fabsf(src[lane + i * 64]));
#pragma unroll
  for (int off = 32; off; off >>= 1) m = fmaxf(m, (float)__shfl_xor(m, off));
  m = fmaxf(m, 1e-20f);
  if (lane == 0){ sw[row] = m / 127.f; swi[row] = 127.f / m; }
}

// Quantize+pack Whh -> i8 A-fragments (K=64), gate-interleaved per kk
__global__ void prep_wi8(const float* __restrict__ Whh, const float* __restrict__ swi,
                         unsigned char* __restrict__ Wp8){
  int gid = blockIdx.x * 256 + threadIdx.x;     // 147456 total
  int lane = gid & 63;
  int r = gid >> 6;
  int g  = r % 3;  r /= 3;
  int kk = r & 7;  r >>= 3;
  int nt = r & 31;
  int l  = r >> 5;
  int row = l * 1536 + g * 512 + nt * 16 + (lane & 15);
  int k0  = kk * 64 + (lane >> 4) * 16;
  const float* src = Whh + (size_t)row * 512 + k0;
  float si = swi[row];
  uint4 v = {0,0,0,0};
  unsigned w[4] = {0,0,0,0};
#pragma unroll
  for (int j = 0; j < 16; ++j){
    int q = (int)rintf(src[j] * si);
    q = q > 127 ? 127 : (q < -127 ? -127 : q);
    w[j >> 2] |= ((unsigned)(q & 0xFF)) << ((j & 3) * 8);
  }
  v.x = w[0]; v.y = w[1]; v.z = w[2]; v.w = w[3];
  *(uint4*)(Wp8 + (size_t)gid * 16) = v;
}

// Pack Wih -> zero-padded (K=8 of 32) bf16 A-fragments, prescaled to exp2 domain
__global__ void prep_wih(const float* __restrict__ Wih, unsigned short* __restrict__ Wip){
  int gid = blockIdx.x * 256 + threadIdx.x;     // 18432 total
  int lane = gid & 63;
  int r = gid >> 6;
  int g  = r % 3;  r /= 3;
  int nt = r & 31;
  int l  = r >> 5;
  float scl = (g == 2) ? LOG2E2 : LOG2E;
  unsigned short t[8] = {0,0,0,0,0,0,0,0};
  if ((lane >> 4) == 0){
    int n = g * 512 + nt * 16 + (lane & 15);
    const float* src = Wih + ((size_t)l * 1536 + n) * 8;
#pragma unroll
    for (int j = 0; j < 8; ++j) t[j] = f2bf(src[j] * scl);
  }
  uint4 v;
  v.x = t[0] | ((unsigned)t[1] << 16);
  v.y = t[2] | ((unsigned)t[3] << 16);
  v.z = t[4] | ((unsigned)t[5] << 16);
  v.w = t[6] | ((unsigned)t[7] << 16);
  *(uint4*)(Wip + (size_t)gid * 8) = v;
}

// Main: 256 blocks x 1024 threads (16 waves), 1 block/CU. R11 structure (proven, 2837us)
// with ONE change: 2-slot named-register weight pipeline (loads issued 2 kk ahead), and
// gi MFMA + bias/scale loads moved AFTER the kk loop to free registers for the slots.
// Sync/exchange path byte-identical to R11 (agent-scope atomics; no sc0, no XCD games).
__global__ __launch_bounds__(1024) void gru_main(
    const float* __restrict__ x,
    const unsigned char* __restrict__ Wp8,
    const unsigned short* __restrict__ Wip,
    const float* __restrict__ bih,
    const float* __restrict__ bhh,
    const float* __restrict__ sw,
    float* __restrict__ out,
    int* __restrict__ flags,
    unsigned int* __restrict__ xchg)
{
  __shared__ __align__(16) unsigned char  hB8[2][32 * H8STR]; // 33,792 B
  __shared__ __align__(16) unsigned short xpack[2][1024];     //  4,096 B
  __shared__ __align__(16) float sBrz[3 * 1024];              // 12,288 B
  __shared__ __align__(16) float sBni[3 * 512];               //  6,144 B
  __shared__ __align__(16) float sBnh[3 * 512];               //  6,144 B
  __shared__ __align__(16) float sK[4608];                    // 18,432 B
  __shared__ int   pad[1024];                                 //  4,096 B -> 84,992 total

  const int tid  = threadIdx.x;
  const int wv   = tid >> 6;
  const int lane = tid & 63;
  const int l15  = lane & 15;
  const int l4   = lane >> 4;

  const int bid     = blockIdx.x;
  const int bgroup  = ((bid >> 3) << 2) | (bid & 3);   // [0,128)
  const int half    = (bid >> 2) & 1;
  const int partner = bid ^ 4;
  const int b0      = bgroup * 32;
  const int lc      = wv * 16 + l4 * 4;                // local col, lane's first of 4
  const int colv    = half * 256 + lc;                 // global col
  const int ntc     = half * 16 + wv;                  // 16-col tile index
  const int pcb0    = (1 - half) * 256;                // partner col base (bytes)
  const int ko0     = half * 4;                        // own-half kk start
  const int pk0     = 4 - ko0;                         // partner-half kk start

  // pad liveness guard (flags never negative) — prevents LDS DCE (R8 lesson)
  if (flags[bid] == -1) pad[tid] = tid;

  unsigned int* xown = xchg + (size_t)bid * 4096;      // 2 slots x 2048 u32
  const unsigned int* xpb = xchg + (size_t)partner * 4096 + tid;
  const int dOff = (tid >> 6) * H8STR + pcb0 + (tid & 63) * 4;   // +16*H8STR for rows 16..31

  for (int i = tid; i < 2 * 32 * H8STR / 4; i += 1024) ((unsigned*)hB8)[i] = 0;
  for (int i = tid; i < 3072; i += 1024){
    int l = i >> 10, c = i & 1023;
    sBrz[i] = (bih[l * 1536 + c] + bhh[l * 1536 + c]) * LOG2E;
  }
  for (int i = tid; i < 1536; i += 1024){
    int l = i >> 9, c = i & 511;
    sBni[i] = bih[l * 1536 + 1024 + c] * LOG2E2;
    sBnh[i] = bhh[l * 1536 + 1024 + c] * LOG2E2;
  }
  for (int i = tid; i < 4608; i += 1024){
    int g = (i % 1536) >> 9;
    sK[i] = sw[i] * (1.f / 127.f) * (g == 2 ? LOG2E2 : LOG2E);
  }

  float hreg[2][4];   // [batch-frag][outcol q]
#pragma unroll
  for (int nf = 0; nf < 2; ++nf)
#pragma unroll
    for (int qq = 0; qq < 4; ++qq) hreg[nf][qq] = 0.f;

  // xpack writer: entry (m*64+ln)*8+j = x[b0+m*16+(ln&15)][j] for ln<16 else 0
  const int xl = (tid >> 3) & 63;
  const size_t xbase = ((size_t)(b0 + (tid >> 9) * 16 + (xl & 15))) * (S_LEN * IN_D) + (tid & 7);
  const int xvalid = (xl < 16);
  { float xv = xvalid ? x[xbase] : 0.f; xpack[0][tid] = f2bf(xv); }
  __syncthreads();

  const int boff0 = l15 * H8STR + l4 * 16;        // h B-frag nf=0 (batch 0..15), bytes
  const int boff1 = boff0 + 16 * H8STR;           // nf=1 (batch 16..31)

  const unsigned char*  wklB = Wp8 + (size_t)ntc * (8 * 3 * 64 * 16) + (size_t)lane * 16;
  const unsigned short* wilB = Wip + (size_t)ntc * 3 * 512 + (size_t)lane * 8;

#define KSEQ(i) ((i) < 4 ? (ko0 + (i)) : (pk0 + (i) - 4))
#define WLD(S, i) { const unsigned char* w_ = wkl + KSEQ(i) * 3072; \
    wR##S = *(const i32x4*)(w_); \
    wZ##S = *(const i32x4*)(w_ + 1024); \
    wN##S = *(const i32x4*)(w_ + 2048); }
#define CONS(S, i) { \
    i32x4 hb0 = *(const i32x4*)(hb8c + boff0 + KSEQ(i) * 64); \
    i32x4 hb1 = *(const i32x4*)(hb8c + boff1 + KSEQ(i) * 64); \
    aR[0] = MFMAI(wR##S, hb0, aR[0]);  aR[1] = MFMAI(wR##S, hb1, aR[1]); \
    aZ[0] = MFMAI(wZ##S, hb0, aZ[0]);  aZ[1] = MFMAI(wZ##S, hb1, aZ[1]); \
    aN[0] = MFMAI(wN##S, hb0, aN[0]);  aN[1] = MFMAI(wN##S, hb1, aN[1]); }

  int cur = 0;
#pragma unroll 1
  for (int t = 0; t < S_LEN; ++t){
    const unsigned short* xp = &xpack[t & 1][0];
#pragma unroll 1
    for (int l = 0; l < NL; ++l){
      const int s    = t * NL + l;
      const int last = (s == S_LEN * NL - 1);
      const unsigned char* hb8c = hB8[cur];
      unsigned char*       hb8w = hB8[cur];
      unsigned char*       hb8n = hB8[cur ^ 1];
      const unsigned char*  wkl = wklB + (size_t)l * (32 * 8 * 3 * 64 * 16);
      const unsigned short* wil = wilB + (size_t)l * (32 * 3 * 512);

      // ---- poll partner + issue 2 mailbox u32 loads (R11-identical) ----
      unsigned c0 = 0, c1 = 0;
      if (s > 0){
        while (__hip_atomic_load(&flags[partner], __ATOMIC_RELAXED, __HIP_MEMORY_SCOPE_AGENT) < s)
          __builtin_amdgcn_s_sleep(4);
        const unsigned int* src = xpb + ((s - 1) & 1) * 2048;
        c0 = __hip_atomic_load(src,        __ATOMIC_RELAXED, __HIP_MEMORY_SCOPE_AGENT);
        c1 = __hip_atomic_load(src + 1024, __ATOMIC_RELAXED, __HIP_MEMORY_SCOPE_AGENT);
      }

      // ---- weight pipeline: 2 named slots, loads issued 2 kk ahead ----
      i32x4 wRa, wZa, wNa, wRb, wZb, wNb;
      WLD(a, 0)  WLD(b, 1)

      i32x4 aR[2], aZ[2], aN[2];
#pragma unroll
      for (int nf = 0; nf < 2; ++nf){
        aR[nf] = (i32x4){0,0,0,0};
        aZ[nf] = (i32x4){0,0,0,0};
        aN[nf] = (i32x4){0,0,0,0};
      }

      // own-half kks (read only own h cols, valid before barrier)
      CONS(a, 0)  WLD(a, 2)
      CONS(b, 1)  WLD(b, 3)
      CONS(a, 2)  WLD(a, 4)
      CONS(b, 3)  WLD(b, 5)

      // partner-copy LDS writes (compiler waits on c0/c1 only) + mid-barrier
      if (s > 0){
        *(unsigned*)(hb8w + dOff)              = c0;
        *(unsigned*)(hb8w + dOff + 16 * H8STR) = c1;
      }
      __syncthreads();

      // gi weight loads issued here: 4 CONS clusters of cover before consumption
      short8 wiR = *(const short8*)(wil);
      short8 wiZ = *(const short8*)(wil + 512);
      short8 wiN = *(const short8*)(wil + 1024);

      // partner-half kks
      CONS(a, 4)  WLD(a, 6)
      CONS(b, 5)  WLD(b, 7)
      CONS(a, 6)
      CONS(b, 7)

      // ---- gi = Wih-frag (A) x x-frag (B) + biases (loaded HERE, after kk loop) ----
      const f32x4 vR4  = *(const f32x4*)&sBrz[l * 1024 + colv];
      const f32x4 vZ4  = *(const f32x4*)&sBrz[l * 1024 + 512 + colv];
      const f32x4 vNi4 = *(const f32x4*)&sBni[l * 512 + colv];
      const f32x4 vNh4 = *(const f32x4*)&sBnh[l * 512 + colv];
      const f32x4 kR4  = *(const f32x4*)&sK[l * 1536 + colv];
      const f32x4 kZ4  = *(const f32x4*)&sK[l * 1536 + 512 + colv];
      const f32x4 kN4  = *(const f32x4*)&sK[l * 1536 + 1024 + colv];

      f32x4 gR[2], gZ[2], gN[2];
      gR[0] = vR4;  gR[1] = vR4;
      gZ[0] = vZ4;  gZ[1] = vZ4;
      gN[0] = vNi4; gN[1] = vNi4;
      {
        short8 xb0 = *(const short8*)(xp + lane * 8);
        short8 xb1 = *(const short8*)(xp + 512 + lane * 8);
        gR[0] = MFMA(wiR, xb0, gR[0]);  gR[1] = MFMA(wiR, xb1, gR[1]);
        gZ[0] = MFMA(wiZ, xb0, gZ[0]);  gZ[1] = MFMA(wiZ, xb1, gZ[1]);
        gN[0] = MFMA(wiN, xb0, gN[0]);  gN[1] = MFMA(wiN, xb1, gN[1]);
      }

      // ---- gates: exp2-domain, native rcp; lane owns 4 consecutive out-cols ----
      unsigned int* xob = xown + (s & 1) * 2048;
#pragma unroll
      for (int nf = 0; nf < 2; ++nf){
        unsigned pk = 0;
#pragma unroll
        for (int qq = 0; qq < 4; ++qq){
          float rp = gR[nf][qq] + (float)aR[nf][qq] * kR4[qq];
          float zp = gZ[nf][qq] + (float)aZ[nf][qq] * kZ4[qq];
          float r  = frcp(1.f + fexp2(-rp));
          float z  = frcp(1.f + fexp2(-zp));
          float an = gN[nf][qq] + r * ((float)aN[nf][qq] * kN4[qq] + vNh4[qq]);
          float n  = fmaf(-2.f, frcp(1.f + fexp2(an)), 1.f);
          float hn = fmaf(z, hreg[nf][qq] - n, n);
          hreg[nf][qq] = hn;
          int hq = (int)rintf(hn * 127.f);
          pk |= ((unsigned)(hq & 0xFF)) << (qq * 8);
        }
        int brow = nf * 16 + l15;
        *(unsigned*)(hb8n + brow * H8STR + colv) = pk;
        if (!last)
          __hip_atomic_store(xob + brow * 64 + wv * 4 + l4, pk,
                             __ATOMIC_RELAXED, __HIP_MEMORY_SCOPE_AGENT);
      }

      // stage x(t+1) before the end-of-step barrier
      if (l == NL - 1 && t < S_LEN - 1){
        float xv = xvalid ? x[xbase + (size_t)(t + 1) * IN_D] : 0.f;
        xpack[(t + 1) & 1][tid] = f2bf(xv);
      }

      if (!last){
        asm volatile("s_waitcnt vmcnt(0)" ::: "memory");   // mailbox stores drained
        __syncthreads();
        if (tid == 0)
          __hip_atomic_store(&flags[bid], s + 1, __ATOMIC_RELAXED, __HIP_MEMORY_SCOPE_AGENT);
      }
      cur ^= 1;
    }
  }
#undef WLD
#undef CONS
#undef KSEQ

  // epilogue: lane holds 4 consecutive out-cols per batch-frag -> dwordx4 stores
#pragma unroll
  for (int nf = 0; nf < 2; ++nf){
    f32x4 v = { hreg[nf][0], hreg[nf][1], hreg[nf][2], hreg[nf][3] };
    int brow = nf * 16 + l15;
    *(f32x4*)&out[((size_t)(b0 + brow)) * 512 + colv] = v;
  }

  if (flags[bid] == -2) out[0] = (float)pad[tid];   // pad liveness (never true)
}

extern "C" void kernel_launch(void* const* d_in, const int* in_sizes, int n_in,
                              void* d_out, int out_size, void* d_ws, size_t ws_size,
                              hipStream_t stream){
  const float* x   = (const float*)d_in[0];
  const float* Wih = (const float*)d_in[1];
  const float* Whh = (const float*)d_in[2];
  const float* bih = (const float*)d_in[3];
  const float* bhh = (const float*)d_in[4];

  unsigned char* ws = (unsigned char*)d_ws;
  unsigned char*  Wp8  = (unsigned char*)(ws + OFF_WI8);
  unsigned short* Wip  = (unsigned short*)(ws + OFF_WIH);
  float*          sw   = (float*)(ws + OFF_SW);
  float*          swi  = (float*)(ws + OFF_SWI);
  int*            flg  = (int*)(ws + OFF_FLAG);
  unsigned int*   xchg = (unsigned int*)(ws + OFF_XCHG);

  hipMemsetAsync(flg, 0, 256 * sizeof(int), stream);
  prep_scale<<<1152, 256, 0, stream>>>(Whh, sw, swi);
  prep_wi8  <<< 576, 256, 0, stream>>>(Whh, swi, Wp8);
  prep_wih  <<<  72, 256, 0, stream>>>(Wih, Wip);
  gru_main  <<< 256, 1024, 0, stream>>>(x, Wp8, Wip, bih, bhh, sw, (float*)d_out, flg, xchg);
}

// Round 15
// 2700.045 us; speedup vs baseline: 1.5617x; 1.0160x over previous
//
#include <hip/hip_runtime.h>

typedef __attribute__((ext_vector_type(8))) short short8;
typedef __attribute__((ext_vector_type(4))) float f32x4;
typedef __attribute__((ext_vector_type(4))) int   i32x4;

#define MFMA(a,b,c)  __builtin_amdgcn_mfma_f32_16x16x32_bf16(a,b,c,0,0,0)
#define MFMAI(a,b,c) __builtin_amdgcn_mfma_i32_16x16x64_i8(a,b,c,0,0,0)

// Problem dims
#define S_LEN 128
#define IN_D  8
#define HID   512
#define NL    3
#define H8STR 528       // i8 h row stride (bytes)
#define LOG2E  1.4426950408889634f
#define LOG2E2 2.8853901617779268f
#define WKL_STRIDE ((size_t)(32 * 8 * 3 * 64 * 16))

// ws layout (bytes)
#define OFF_WI8  0                       // [3][32nt][8kk][3g][64][16B] i8 = 2,359,296
#define OFF_WIH  (2359296)               // [3][32][3][64][8] bf16        =   294,912
#define OFF_SW   (2359296 + 294912)      // 4608 f32 dequant scales       =    18,432
#define OFF_SWI  (OFF_SW + 18432)        // 4608 f32 inv scales           =    18,432
#define OFF_FLAG (OFF_SWI + 18432)       // 256 int                       =     1,024
#define OFF_XCHG (OFF_FLAG + 1024)       // 256 blk * 2 slot * 8 KB       = 4,194,304

__device__ __forceinline__ unsigned short f2bf(float f){
  unsigned u = __float_as_uint(f);
  u += 0x7FFFu + ((u >> 16) & 1u);
  return (unsigned short)(u >> 16);
}
__device__ __forceinline__ float fexp2(float x){ return __builtin_amdgcn_exp2f(x); }
__device__ __forceinline__ float frcp(float x){ return __builtin_amdgcn_rcpf(x); }

// Per-row absmax scales for Whh
__global__ void prep_scale(const float* __restrict__ Whh,
                           float* __restrict__ sw, float* __restrict__ swi){
  int row = blockIdx.x * 4 + (threadIdx.x >> 6);
  int lane = threadIdx.x & 63;
  const float* src = Whh + (size_t)row * 512;
  float m = 0.f;
#pragma unroll
  for (int i = 0; i < 8; ++i) m = fmaxf(m, fabsf(src[lane + i * 64]));
#pragma unroll
  for (int off = 32; off; off >>= 1) m = fmaxf(m, (float)__shfl_xor(m, off));
  m = fmaxf(m, 1e-20f);
  if (lane == 0){ sw[row] = m / 127.f; swi[row] = 127.f / m; }
}

// Quantize+pack Whh -> i8 A-fragments (K=64), gate-interleaved per kk
__global__ void prep_wi8(const float* __restrict__ Whh, const float* __restrict__ swi,
                         unsigned char* __restrict__ Wp8){
  int gid = blockIdx.x * 256 + threadIdx.x;     // 147456 total
  int lane = gid & 63;
  int r = gid >> 6;
  int g  = r % 3;  r /= 3;
  int kk = r & 7;  r >>= 3;
  int nt = r & 31;
  int l  = r >> 5;
  int row = l * 1536 + g * 512 + nt * 16 + (lane & 15);
  int k0  = kk * 64 + (lane >> 4) * 16;
  const float* src = Whh + (size_t)row * 512 + k0;
  float si = swi[row];
  uint4 v = {0,0,0,0};
  unsigned w[4] = {0,0,0,0};
#pragma unroll
  for (int j = 0; j < 16; ++j){
    int q = (int)rintf(src[j] * si);
    q = q > 127 ? 127 : (q < -127 ? -127 : q);
    w[j >> 2] |= ((unsigned)(q & 0xFF)) << ((j & 3) * 8);
  }
  v.x = w[0]; v.y = w[1]; v.z = w[2]; v.w = w[3];
  *(uint4*)(Wp8 + (size_t)gid * 16) = v;
}

// Pack Wih -> zero-padded (K=8 of 32) bf16 A-fragments, prescaled to exp2 domain
__global__ void prep_wih(const float* __restrict__ Wih, unsigned short* __restrict__ Wip){
  int gid = blockIdx.x * 256 + threadIdx.x;     // 18432 total
  int lane = gid & 63;
  int r = gid >> 6;
  int g  = r % 3;  r /= 3;
  int nt = r & 31;
  int l  = r >> 5;
  float scl = (g == 2) ? LOG2E2 : LOG2E;
  unsigned short t[8] = {0,0,0,0,0,0,0,0};
  if ((lane >> 4) == 0){
    int n = g * 512 + nt * 16 + (lane & 15);
    const float* src = Wih + ((size_t)l * 1536 + n) * 8;
#pragma unroll
    for (int j = 0; j < 8; ++j) t[j] = f2bf(src[j] * scl);
  }
  uint4 v;
  v.x = t[0] | ((unsigned)t[1] << 16);
  v.y = t[2] | ((unsigned)t[3] << 16);
  v.z = t[4] | ((unsigned)t[5] << 16);
  v.w = t[6] | ((unsigned)t[7] << 16);
  *(uint4*)(Wip + (size_t)gid * 8) = v;
}

// Main: R14 structure (proven, 2743us) + (1) cross-step weight-slot prefetch
// (pipeline never cold-starts; loads covered by gates+barrier of previous step)
// + (2) non-draining mid-barrier (lgkmcnt-only + raw s_barrier: weight loads
// stay in flight across it). Sync/exchange topology identical to R11/R14.
__global__ __launch_bounds__(1024) void gru_main(
    const float* __restrict__ x,
    const unsigned char* __restrict__ Wp8,
    const unsigned short* __restrict__ Wip,
    const float* __restrict__ bih,
    const float* __restrict__ bhh,
    const float* __restrict__ sw,
    float* __restrict__ out,
    int* __restrict__ flags,
    unsigned int* __restrict__ xchg)
{
  __shared__ __align__(16) unsigned char  hB8[2][32 * H8STR]; // 33,792 B
  __shared__ __align__(16) unsigned short xpack[2][1024];     //  4,096 B
  __shared__ __align__(16) float sBrz[3 * 1024];              // 12,288 B
  __shared__ __align__(16) float sBni[3 * 512];               //  6,144 B
  __shared__ __align__(16) float sBnh[3 * 512];               //  6,144 B
  __shared__ __align__(16) float sK[4608];                    // 18,432 B
  __shared__ int   pad[1024];                                 //  4,096 B -> 84,992 total

  const int tid  = threadIdx.x;
  const int wv   = tid >> 6;
  const int lane = tid & 63;
  const int l15  = lane & 15;
  const int l4   = lane >> 4;

  const int bid     = blockIdx.x;
  const int bgroup  = ((bid >> 3) << 2) | (bid & 3);   // [0,128)
  const int half    = (bid >> 2) & 1;
  const int partner = bid ^ 4;
  const int b0      = bgroup * 32;
  const int lc      = wv * 16 + l4 * 4;                // local col, lane's first of 4
  const int colv    = half * 256 + lc;                 // global col
  const int ntc     = half * 16 + wv;                  // 16-col tile index
  const int pcb0    = (1 - half) * 256;                // partner col base (bytes)
  const int ko0     = half * 4;                        // own-half kk start
  const int pk0     = 4 - ko0;                         // partner-half kk start

  // pad liveness guard (flags never negative) — prevents LDS DCE (R8 lesson)
  if (flags[bid] == -1) pad[tid] = tid;

  unsigned int* xown = xchg + (size_t)bid * 4096;      // 2 slots x 2048 u32
  const unsigned int* xpb = xchg + (size_t)partner * 4096 + tid;
  const int dOff = (tid >> 6) * H8STR + pcb0 + (tid & 63) * 4;   // +16*H8STR for rows 16..31

  for (int i = tid; i < 2 * 32 * H8STR / 4; i += 1024) ((unsigned*)hB8)[i] = 0;
  for (int i = tid; i < 3072; i += 1024){
    int l = i >> 10, c = i & 1023;
    sBrz[i] = (bih[l * 1536 + c] + bhh[l * 1536 + c]) * LOG2E;
  }
  for (int i = tid; i < 1536; i += 1024){
    int l = i >> 9, c = i & 511;
    sBni[i] = bih[l * 1536 + 1024 + c] * LOG2E2;
    sBnh[i] = bhh[l * 1536 + 1024 + c] * LOG2E2;
  }
  for (int i = tid; i < 4608; i += 1024){
    int g = (i % 1536) >> 9;
    sK[i] = sw[i] * (1.f / 127.f) * (g == 2 ? LOG2E2 : LOG2E);
  }

  float hreg[2][4];   // [batch-frag][outcol q]
#pragma unroll
  for (int nf = 0; nf < 2; ++nf)
#pragma unroll
    for (int qq = 0; qq < 4; ++qq) hreg[nf][qq] = 0.f;

  // xpack writer: entry (m*64+ln)*8+j = x[b0+m*16+(ln&15)][j] for ln<16 else 0
  const int xl = (tid >> 3) & 63;
  const size_t xbase = ((size_t)(b0 + (tid >> 9) * 16 + (xl & 15))) * (S_LEN * IN_D) + (tid & 7);
  const int xvalid = (xl < 16);
  { float xv = xvalid ? x[xbase] : 0.f; xpack[0][tid] = f2bf(xv); }
  __syncthreads();

  const int boff0 = l15 * H8STR + l4 * 16;        // h B-frag nf=0 (batch 0..15), bytes
  const int boff1 = boff0 + 16 * H8STR;           // nf=1 (batch 16..31)

  const unsigned char*  wklB = Wp8 + (size_t)ntc * (8 * 3 * 64 * 16) + (size_t)lane * 16;
  const unsigned short* wilB = Wip + (size_t)ntc * 3 * 512 + (size_t)lane * 8;

#define KSEQ(i) ((i) < 4 ? (ko0 + (i)) : (pk0 + (i) - 4))
#define WLD(S, i, P) { const unsigned char* w_ = (P) + KSEQ(i) * 3072; \
    wR##S = *(const i32x4*)(w_); \
    wZ##S = *(const i32x4*)(w_ + 1024); \
    wN##S = *(const i32x4*)(w_ + 2048); }
#define CONS(S, i) { \
    i32x4 hb0 = *(const i32x4*)(hb8c + boff0 + KSEQ(i) * 64); \
    i32x4 hb1 = *(const i32x4*)(hb8c + boff1 + KSEQ(i) * 64); \
    aR[0] = MFMAI(wR##S, hb0, aR[0]);  aR[1] = MFMAI(wR##S, hb1, aR[1]); \
    aZ[0] = MFMAI(wZ##S, hb0, aZ[0]);  aZ[1] = MFMAI(wZ##S, hb1, aZ[1]); \
    aN[0] = MFMAI(wN##S, hb0, aN[0]);  aN[1] = MFMAI(wN##S, hb1, aN[1]); }

  // loop-carried weight pipeline slots; prologue fill for (t=0, l=0)
  i32x4 wRa, wZa, wNa, wRb, wZb, wNb;
  WLD(a, 0, wklB)  WLD(b, 1, wklB)

  int cur = 0;
#pragma unroll 1
  for (int t = 0; t < S_LEN; ++t){
    const unsigned short* xp = &xpack[t & 1][0];
#pragma unroll 1
    for (int l = 0; l < NL; ++l){
      const int s    = t * NL + l;
      const int last = (s == S_LEN * NL - 1);
      const unsigned char* hb8c = hB8[cur];
      unsigned char*       hb8w = hB8[cur];
      unsigned char*       hb8n = hB8[cur ^ 1];
      const unsigned char*  wkl = wklB + (size_t)l * WKL_STRIDE;
      const unsigned short* wil = wilB + (size_t)l * (32 * 3 * 512);

      // ---- poll partner + issue 2 mailbox u32 loads (R11-identical) ----
      unsigned c0 = 0, c1 = 0;
      if (s > 0){
        while (__hip_atomic_load(&flags[partner], __ATOMIC_RELAXED, __HIP_MEMORY_SCOPE_AGENT) < s)
          __builtin_amdgcn_s_sleep(4);
        const unsigned int* src = xpb + ((s - 1) & 1) * 2048;
        c0 = __hip_atomic_load(src,        __ATOMIC_RELAXED, __HIP_MEMORY_SCOPE_AGENT);
        c1 = __hip_atomic_load(src + 1024, __ATOMIC_RELAXED, __HIP_MEMORY_SCOPE_AGENT);
      }

      i32x4 aR[2], aZ[2], aN[2];
#pragma unroll
      for (int nf = 0; nf < 2; ++nf){
        aR[nf] = (i32x4){0,0,0,0};
        aZ[nf] = (i32x4){0,0,0,0};
        aN[nf] = (i32x4){0,0,0,0};
      }

      // own-half kks: slots a,b were prefetched LAST step -> no cold start
      CONS(a, 0)  WLD(a, 2, wkl)
      CONS(b, 1)  WLD(b, 3, wkl)
      CONS(a, 2)  WLD(a, 4, wkl)
      CONS(b, 3)  WLD(b, 5, wkl)

      // partner-copy LDS writes; NON-DRAINING mid-barrier (lgkm only —
      // weight loads 4,5 stay in flight across it; c0/c1 use is counted-vmcnt)
      if (s > 0){
        *(unsigned*)(hb8w + dOff)              = c0;
        *(unsigned*)(hb8w + dOff + 16 * H8STR) = c1;
      }
      asm volatile("s_waitcnt lgkmcnt(0)" ::: "memory");
      __builtin_amdgcn_s_barrier();

      // gi weight loads: 4 CONS clusters of cover before consumption
      short8 wiR = *(const short8*)(wil);
      short8 wiZ = *(const short8*)(wil + 512);
      short8 wiN = *(const short8*)(wil + 1024);

      // partner-half kks
      CONS(a, 4)  WLD(a, 6, wkl)
      CONS(b, 5)  WLD(b, 7, wkl)
      CONS(a, 6)
      CONS(b, 7)

      // cross-step prefetch: fill slots for next step's kk seq 0,1 (no h/flag dep;
      // end-of-step vmcnt(0)+barrier+gates are the latency cover)
      {
        const unsigned char* wkn = wklB + (size_t)(l == NL - 1 ? 0 : l + 1) * WKL_STRIDE;
        WLD(a, 0, wkn)  WLD(b, 1, wkn)
      }

      // ---- gi = Wih-frag (A) x x-frag (B) + biases ----
      const f32x4 vR4  = *(const f32x4*)&sBrz[l * 1024 + colv];
      const f32x4 vZ4  = *(const f32x4*)&sBrz[l * 1024 + 512 + colv];
      const f32x4 vNi4 = *(const f32x4*)&sBni[l * 512 + colv];
      const f32x4 vNh4 = *(const f32x4*)&sBnh[l * 512 + colv];
      const f32x4 kR4  = *(const f32x4*)&sK[l * 1536 + colv];
      const f32x4 kZ4  = *(const f32x4*)&sK[l * 1536 + 512 + colv];
      const f32x4 kN4  = *(const f32x4*)&sK[l * 1536 + 1024 + colv];

      f32x4 gR[2], gZ[2], gN[2];
      gR[0] = vR4;  gR[1] = vR4;
      gZ[0] = vZ4;  gZ[1] = vZ4;
      gN[0] = vNi4; gN[1] = vNi4;
      {
        short8 xb0 = *(const short8*)(xp + lane * 8);
        short8 xb1 = *(const short8*)(xp + 512 + lane * 8);
        gR[0] = MFMA(wiR, xb0, gR[0]);  gR[1] = MFMA(wiR, xb1, gR[1]);
        gZ[0] = MFMA(wiZ, xb0, gZ[0]);  gZ[1] = MFMA(wiZ, xb1, gZ[1]);
        gN[0] = MFMA(wiN, xb0, gN[0]);  gN[1] = MFMA(wiN, xb1, gN[1]);
      }

      // ---- gates: exp2-domain, native rcp; lane owns 4 consecutive out-cols ----
      unsigned int* xob = xown + (s & 1) * 2048;
#pragma unroll
      for (int nf = 0; nf < 2; ++nf){
        unsigned pk = 0;
#pragma unroll
        for (int qq = 0; qq < 4; ++qq){
          float rp = gR[nf][qq] + (float)aR[nf][qq] * kR4[qq];
          float zp = gZ[nf][qq] + (float)aZ[nf][qq] * kZ4[qq];
          float r  = frcp(1.f + fexp2(-rp));
          float z  = frcp(1.f + fexp2(-zp));
          float an = gN[nf][qq] + r * ((float)aN[nf][qq] * kN4[qq] + vNh4[qq]);
          float n  = fmaf(-2.f, frcp(1.f + fexp2(an)), 1.f);
          float hn = fmaf(z, hreg[nf][qq] - n, n);
          hreg[nf][qq] = hn;
          int hq = (int)rintf(hn * 127.f);
          pk |= ((unsigned)(hq & 0xFF)) << (qq * 8);
        }
        int brow = nf * 16 + l15;
        *(unsigned*)(hb8n + brow * H8STR + colv) = pk;
        if (!last)
          __hip_atomic_store(xob + brow * 64 + wv * 4 + l4, pk,
                             __ATOMIC_RELAXED, __HIP_MEMORY_SCOPE_AGENT);
      }

      // stage x(t+1) before the end-of-step barrier
      if (l == NL - 1 && t < S_LEN - 1){
        float xv = xvalid ? x[xbase + (size_t)(t + 1) * IN_D] : 0.f;
        xpack[(t + 1) & 1][tid] = f2bf(xv);
      }

      if (!last){
        asm volatile("s_waitcnt vmcnt(0)" ::: "memory");   // mailbox stores drained
        __syncthreads();
        if (tid == 0)
          __hip_atomic_store(&flags[bid], s + 1, __ATOMIC_RELAXED, __HIP_MEMORY_SCOPE_AGENT);
      }
      cur ^= 1;
    }
  }
#undef WLD
#undef CONS
#undef KSEQ

  // epilogue: lane holds 4 consecutive out-cols per batch-frag -> dwordx4 stores
#pragma unroll
  for (int nf = 0; nf < 2; ++nf){
    f32x4 v = { hreg[nf][0], hreg[nf][1], hreg[nf][2], hreg[nf][3] };
    int brow = nf * 16 + l15;
    *(f32x4*)&out[((size_t)(b0 + brow)) * 512 + colv] = v;
  }

  if (flags[bid] == -2) out[0] = (float)pad[tid];   // pad liveness (never true)
}

extern "C" void kernel_launch(void* const* d_in, const int* in_sizes, int n_in,
                              void* d_out, int out_size, void* d_ws, size_t ws_size,
                              hipStream_t stream){
  const float* x   = (const float*)d_in[0];
  const float* Wih = (const float*)d_in[1];
  const float* Whh = (const float*)d_in[2];
  const float* bih = (const float*)d_in[3];
  const float* bhh = (const float*)d_in[4];

  unsigned char* ws = (unsigned char*)d_ws;
  unsigned char*  Wp8  = (unsigned char*)(ws + OFF_WI8);
  unsigned short* Wip  = (unsigned short*)(ws + OFF_WIH);
  float*          sw   = (float*)(ws + OFF_SW);
  float*          swi  = (float*)(ws + OFF_SWI);
  int*            flg  = (int*)(ws + OFF_FLAG);
  unsigned int*   xchg = (unsigned int*)(ws + OFF_XCHG);

  hipMemsetAsync(flg, 0, 256 * sizeof(int), stream);
  prep_scale<<<1152, 256, 0, stream>>>(Whh, sw, swi);
  prep_wi8  <<< 576, 256, 0, stream>>>(Whh, swi, Wp8);
  prep_wih  <<<  72, 256, 0, stream>>>(Wih, Wip);
  gru_main  <<< 256, 1024, 0, stream>>>(x, Wp8, Wip, bih, bhh, sw, (float*)d_out, flg, xchg);
}